// Round 1
// baseline (1961.735 us; speedup 1.0000x reference)
//
#include <hip/hip_runtime.h>
#include <math.h>

#define DIN 128
#define DH  128
#define DOUT 64
#define EPSF 1e-8f
#define LN_EPS 1e-5f

// ---------------- node kernels ----------------

// one wave (64 lanes) per node, 2 floats per lane
__global__ __launch_bounds__(256) void node_norm_k(const float* __restrict__ feat,
                                                   float* __restrict__ nrm, int n) {
    int wid  = (blockIdx.x * 256 + threadIdx.x) >> 6;
    int lane = threadIdx.x & 63;
    if (wid >= n) return;
    float2 v = *(const float2*)(feat + (size_t)wid * 128 + lane * 2);
    float s = v.x * v.x + v.y * v.y;
    #pragma unroll
    for (int off = 32; off; off >>= 1) s += __shfl_xor(s, off, 64);
    if (lane == 0) nrm[wid] = fmaxf(sqrtf(s), EPSF);
}

__global__ __launch_bounds__(256) void node_b_k(const float* __restrict__ deg1,
                                                const float* __restrict__ cntf,
                                                float* __restrict__ dinv1,
                                                float* __restrict__ wself, int n) {
    int i = blockIdx.x * 256 + threadIdx.x;
    if (i >= n) return;
    float d = deg1[i];
    dinv1[i] = (d > 0.0f) ? 1.0f / sqrtf(d) : 0.0f;
    wself[i] = expf(1.0f / (cntf[i] + 1.0f));
}

__global__ __launch_bounds__(256) void node_d_k(const float* __restrict__ deg2,
                                                const float* __restrict__ wself,
                                                float* __restrict__ dinv2,
                                                float* __restrict__ cself, int n) {
    int i = blockIdx.x * 256 + threadIdx.x;
    if (i >= n) return;
    float dg = deg2[i] + wself[i];            // self-loop weight included in degree
    float di = (dg > 0.0f) ? 1.0f / sqrtf(dg) : 0.0f;
    dinv2[i] = di;
    cself[i] = di * di * wself[i];            // self-edge normalized weight
}

// ---------------- edge kernels ----------------

// 32 lanes per edge: cosine similarity + masking + degree atomics
__global__ __launch_bounds__(256) void edge_dot_k(const float* __restrict__ feat,
    const int* __restrict__ row, const int* __restrict__ col,
    const float* __restrict__ nrm, float* __restrict__ simsE,
    float* __restrict__ deg1, float* __restrict__ cntf, int ecnt) {
    int gid = blockIdx.x * 256 + threadIdx.x;
    int e = gid >> 5;
    if (e >= ecnt) return;
    int l = gid & 31;
    int r = row[e], c = col[e];
    float4 a = *(const float4*)(feat + (size_t)r * 128 + l * 4);
    float4 b = *(const float4*)(feat + (size_t)c * 128 + l * 4);
    float s = a.x * b.x + a.y * b.y + a.z * b.z + a.w * b.w;
    #pragma unroll
    for (int off = 16; off; off >>= 1) s += __shfl_xor(s, off, 32);
    if (l == 0) {
        float sim  = s / (nrm[r] * nrm[c]);
        float kept = (sim >= 0.1f) ? sim : 0.0f;
        simsE[e] = kept;
        if (kept > 0.0f) {
            atomicAdd(&deg1[r], kept);
            atomicAdd(&cntf[c], 1.0f);
        }
    }
}

// vals = exp(dinv1[row]*sim*dinv1[col]) for kept edges; accumulate gcn degree over col
__global__ __launch_bounds__(256) void edge_c_k(float* __restrict__ simsE,
    const int* __restrict__ row, const int* __restrict__ col,
    const float* __restrict__ dinv1, float* __restrict__ deg2, int ecnt) {
    int e = blockIdx.x * 256 + threadIdx.x;
    if (e >= ecnt) return;
    float s = simsE[e];
    if (s > 0.0f) {
        float v = expf(dinv1[row[e]] * s * dinv1[col[e]]);
        simsE[e] = v;                         // buffer now holds vals
        atomicAdd(&deg2[col[e]], v);
    }
}

// final per-edge gcn weight + compaction of surviving edges
__global__ __launch_bounds__(256) void edge_compact_k(const float* __restrict__ simsE,
    const int* __restrict__ row, const int* __restrict__ col,
    const float* __restrict__ dinv2, int* __restrict__ rowC, int* __restrict__ colC,
    float* __restrict__ wC, int* __restrict__ kcnt, int ecnt) {
    int e = blockIdx.x * 256 + threadIdx.x;
    if (e >= ecnt) return;
    float v = simsE[e];
    if (v > 0.0f) {
        int r = row[e], c = col[e];
        float w = v * dinv2[r] * dinv2[c];
        int p = atomicAdd(kcnt, 1);
        rowC[p] = r; colC[p] = c; wC[p] = w;
    }
}

// ---------------- GEMM: out[n][:] = A[n][:] @ W (K=128) ----------------

template<int ODIM>
__global__ __launch_bounds__(256) void gemm_k(const float* __restrict__ A,
    const float* __restrict__ W, float* __restrict__ out, int n) {
    constexpr int TPN = ODIM / 4;     // threads per node
    constexpr int NPB = 256 / TPN;    // nodes per block
    __shared__ float Ws[128 * ODIM];
    for (int i = threadIdx.x; i < 128 * ODIM / 4; i += 256)
        ((float4*)Ws)[i] = ((const float4*)W)[i];
    __syncthreads();
    int nid = blockIdx.x * NPB + (int)(threadIdx.x / TPN);
    if (nid >= n) return;
    int dbase = (threadIdx.x % TPN) * 4;
    const float4* a = (const float4*)(A + (size_t)nid * 128);
    float ax = 0.f, ay = 0.f, az = 0.f, aw = 0.f;
    #pragma unroll 4
    for (int k4 = 0; k4 < 32; ++k4) {
        float4 av = a[k4];
        const float* wr = Ws + (k4 * 4) * ODIM + dbase;
        float4 w0 = *(const float4*)(wr);
        float4 w1 = *(const float4*)(wr + ODIM);
        float4 w2 = *(const float4*)(wr + 2 * ODIM);
        float4 w3 = *(const float4*)(wr + 3 * ODIM);
        ax += av.x * w0.x; ay += av.x * w0.y; az += av.x * w0.z; aw += av.x * w0.w;
        ax += av.y * w1.x; ay += av.y * w1.y; az += av.y * w1.z; aw += av.y * w1.w;
        ax += av.z * w2.x; ay += av.z * w2.y; az += av.z * w2.z; aw += av.z * w2.w;
        ax += av.w * w3.x; ay += av.w * w3.y; az += av.w * w3.z; aw += av.w * w3.w;
    }
    float4 r; r.x = ax; r.y = ay; r.z = az; r.w = aw;
    *(float4*)(out + (size_t)nid * ODIM + dbase) = r;
}

// ---------------- scatter: out[col] += w * h[row] over compacted edges ----------------

template<int ODIM>
__global__ __launch_bounds__(256) void scatter_k(const float* __restrict__ h,
    const int* __restrict__ rowC, const int* __restrict__ colC,
    const float* __restrict__ wC, const int* __restrict__ kcnt,
    float* __restrict__ out) {
    int total = (*kcnt) * ODIM;
    int stride = (int)gridDim.x * 256;
    for (int gid = blockIdx.x * 256 + threadIdx.x; gid < total; gid += stride) {
        int i = gid / ODIM;          // constexpr power of 2 -> shift
        int d = gid % ODIM;
        atomicAdd(&out[(size_t)colC[i] * ODIM + d], wC[i] * h[(size_t)rowC[i] * ODIM + d]);
    }
}

// ---------------- epilogues ----------------

// out = relu(LN(agg + cself*h + bias)); one wave per node, writes into outbuf (may alias h)
__global__ __launch_bounds__(256) void ln_k(const float* __restrict__ agg,
    const float* __restrict__ h, const float* __restrict__ cself,
    const float* __restrict__ bias, const float* __restrict__ g,
    const float* __restrict__ bln, float* __restrict__ outbuf, int n) {
    int wid  = (blockIdx.x * 256 + threadIdx.x) >> 6;
    int lane = threadIdx.x & 63;
    if (wid >= n) return;
    size_t base = (size_t)wid * 128 + lane * 2;
    float cs = cself[wid];
    float2 va  = *(const float2*)(agg + base);
    float2 vh  = *(const float2*)(h + base);
    float2 vb  = *(const float2*)(bias + lane * 2);
    float x0 = va.x + cs * vh.x + vb.x;
    float x1 = va.y + cs * vh.y + vb.y;
    float s = x0 + x1;
    #pragma unroll
    for (int off = 32; off; off >>= 1) s += __shfl_xor(s, off, 64);
    float mu = s * (1.0f / 128.0f);
    float d0 = x0 - mu, d1 = x1 - mu;
    float vv = d0 * d0 + d1 * d1;
    #pragma unroll
    for (int off = 32; off; off >>= 1) vv += __shfl_xor(vv, off, 64);
    float rstd = 1.0f / sqrtf(vv * (1.0f / 128.0f) + LN_EPS);
    float2 vg  = *(const float2*)(g + lane * 2);
    float2 vbl = *(const float2*)(bln + lane * 2);
    float y0 = fmaxf(d0 * rstd * vg.x + vbl.x, 0.0f);
    float y1 = fmaxf(d1 * rstd * vg.y + vbl.y, 0.0f);
    *(float2*)(outbuf + base) = make_float2(y0, y1);
}

// log_softmax(agg + cself*g2 + b2) over 64 dims; one wave per node; out may alias agg
__global__ __launch_bounds__(256) void lsm_k(const float* __restrict__ agg,
    const float* __restrict__ g2, const float* __restrict__ cself,
    const float* __restrict__ b2, float* __restrict__ out, int n) {
    int wid  = (blockIdx.x * 256 + threadIdx.x) >> 6;
    int lane = threadIdx.x & 63;
    if (wid >= n) return;
    size_t base = (size_t)wid * 64;
    float v = agg[base + lane] + cself[wid] * g2[base + lane] + b2[lane];
    float m = v;
    #pragma unroll
    for (int off = 32; off; off >>= 1) m = fmaxf(m, __shfl_xor(m, off, 64));
    float e = expf(v - m);
    float s = e;
    #pragma unroll
    for (int off = 32; off; off >>= 1) s += __shfl_xor(s, off, 64);
    out[base + lane] = v - m - logf(s);
}

// ---------------- launch ----------------

extern "C" void kernel_launch(void* const* d_in, const int* in_sizes, int n_in,
                              void* d_out, int out_size, void* d_ws, size_t ws_size,
                              hipStream_t stream) {
    (void)n_in; (void)out_size; (void)ws_size;
    const float* x   = (const float*)d_in[0];
    const int*   row = (const int*)d_in[1];
    const int*   col = (const int*)d_in[2];
    const float* W1  = (const float*)d_in[3];
    const float* b1  = (const float*)d_in[4];
    const float* lng = (const float*)d_in[5];
    const float* lnb = (const float*)d_in[6];
    const float* W2  = (const float*)d_in[7];
    const float* b2  = (const float*)d_in[8];
    float* out = (float*)d_out;

    const int N = in_sizes[0] / DIN;
    const int E = in_sizes[1];

    float* ws    = (float*)d_ws;
    float* nrm   = ws;
    float* deg1  = nrm + N;      // deg1,cntf,deg2 contiguous: one memset
    float* cntf  = deg1 + N;
    float* deg2  = cntf + N;
    float* dinv1 = deg2 + N;
    float* wself = dinv1 + N;
    float* dinv2 = wself + N;
    float* cself = dinv2 + N;
    int*   kcnt  = (int*)(cself + N);
    float* simsE = cself + N + 256;          // padding keeps float4 alignment downstream
    float* wC    = simsE + E;
    int*   rowC  = (int*)(wC + E);
    int*   colC  = rowC + E;
    float* h1    = (float*)(colC + E);       // [N,128]; later reused as h2
    float* agg1  = h1 + (size_t)N * DH;      // [N,128]; later reused as g2 [N,64]

    const int nodeBlocks  = (N + 255) / 256;
    const int waveBlocks  = (N + 3) / 4;            // 1 wave per node, 4 waves/block
    const int edgeBlocks  = (E + 255) / 256;
    const int edge32Blk   = (int)(((size_t)E * 32 + 255) / 256);

    // ================= layer 1 =================
    hipMemsetAsync(deg1, 0, 3 * (size_t)N * sizeof(float), stream);
    hipMemsetAsync(kcnt, 0, sizeof(int), stream);

    node_norm_k<<<waveBlocks, 256, 0, stream>>>(x, nrm, N);
    edge_dot_k<<<edge32Blk, 256, 0, stream>>>(x, row, col, nrm, simsE, deg1, cntf, E);
    node_b_k<<<nodeBlocks, 256, 0, stream>>>(deg1, cntf, dinv1, wself, N);
    edge_c_k<<<edgeBlocks, 256, 0, stream>>>(simsE, row, col, dinv1, deg2, E);
    node_d_k<<<nodeBlocks, 256, 0, stream>>>(deg2, wself, dinv2, cself, N);
    edge_compact_k<<<edgeBlocks, 256, 0, stream>>>(simsE, row, col, dinv2, rowC, colC, wC, kcnt, E);

    gemm_k<DH><<<(N + 7) / 8, 256, 0, stream>>>(x, W1, h1, N);
    hipMemsetAsync(agg1, 0, (size_t)N * DH * sizeof(float), stream);
    scatter_k<DH><<<4096, 256, 0, stream>>>(h1, rowC, colC, wC, kcnt, agg1);
    ln_k<<<waveBlocks, 256, 0, stream>>>(agg1, h1, cself, b1, lng, lnb, h1, N);  // h1 := h2

    // ================= layer 2 =================
    hipMemsetAsync(deg1, 0, 3 * (size_t)N * sizeof(float), stream);
    hipMemsetAsync(kcnt, 0, sizeof(int), stream);

    node_norm_k<<<waveBlocks, 256, 0, stream>>>(h1, nrm, N);
    edge_dot_k<<<edge32Blk, 256, 0, stream>>>(h1, row, col, nrm, simsE, deg1, cntf, E);
    node_b_k<<<nodeBlocks, 256, 0, stream>>>(deg1, cntf, dinv1, wself, N);
    edge_c_k<<<edgeBlocks, 256, 0, stream>>>(simsE, row, col, dinv1, deg2, E);
    node_d_k<<<nodeBlocks, 256, 0, stream>>>(deg2, wself, dinv2, cself, N);
    edge_compact_k<<<edgeBlocks, 256, 0, stream>>>(simsE, row, col, dinv2, rowC, colC, wC, kcnt, E);

    gemm_k<DOUT><<<(N + 15) / 16, 256, 0, stream>>>(h1, W2, agg1, N);   // agg1 := g2
    hipMemsetAsync(out, 0, (size_t)N * DOUT * sizeof(float), stream);
    scatter_k<DOUT><<<4096, 256, 0, stream>>>(agg1, rowC, colC, wC, kcnt, out);
    lsm_k<<<waveBlocks, 256, 0, stream>>>(out, agg1, cself, b2, out, N);
}

// Round 2
// 1219.180 us; speedup vs baseline: 1.6091x; 1.6091x over previous
//
#include <hip/hip_runtime.h>
#include <math.h>

#define EPSF 1e-8f
#define LN_EPS 1e-5f

// ---------------- node kernels ----------------

// one wave (64 lanes) per node, 2 floats per lane
__global__ __launch_bounds__(256) void node_norm_k(const float* __restrict__ feat,
                                                   float* __restrict__ nrm, int n) {
    int wid  = (blockIdx.x * 256 + threadIdx.x) >> 6;
    int lane = threadIdx.x & 63;
    if (wid >= n) return;
    float2 v = *(const float2*)(feat + (size_t)wid * 128 + lane * 2);
    float s = v.x * v.x + v.y * v.y;
    #pragma unroll
    for (int off = 32; off; off >>= 1) s += __shfl_xor(s, off, 64);
    if (lane == 0) nrm[wid] = fmaxf(sqrtf(s), EPSF);
}

__global__ __launch_bounds__(256) void node_b_k(const float* __restrict__ deg1,
                                                const int* __restrict__ cnt,
                                                float* __restrict__ dinv1,
                                                float* __restrict__ wself, int n) {
    int i = blockIdx.x * 256 + threadIdx.x;
    if (i >= n) return;
    float d = deg1[i];
    dinv1[i] = (d > 0.0f) ? 1.0f / sqrtf(d) : 0.0f;
    wself[i] = expf(1.0f / ((float)cnt[i] + 1.0f));
}

__global__ __launch_bounds__(256) void node_d_k(const float* __restrict__ deg2,
                                                const float* __restrict__ wself,
                                                float* __restrict__ dinv2,
                                                float* __restrict__ cself, int n) {
    int i = blockIdx.x * 256 + threadIdx.x;
    if (i >= n) return;
    float dg = deg2[i] + wself[i];            // self-loop weight always > 0
    float di = 1.0f / sqrtf(dg);
    dinv2[i] = di;
    cself[i] = di * di * wself[i];            // normalized self-edge weight
}

// ---------------- edge kernels ----------------

// 32 lanes per edge: cosine similarity + mask; deg1 (float, by row) and cnt (int, by col)
__global__ __launch_bounds__(256) void edge_dot_k(const float* __restrict__ feat,
    const int* __restrict__ row, const int* __restrict__ col,
    const float* __restrict__ nrm, float* __restrict__ simsE,
    float* __restrict__ deg1, int* __restrict__ cnt, int ecnt) {
    int gid = blockIdx.x * 256 + threadIdx.x;
    int e = gid >> 5;
    if (e >= ecnt) return;
    int l = gid & 31;
    int r = row[e], c = col[e];
    float4 a = *(const float4*)(feat + (size_t)r * 128 + l * 4);
    float4 b = *(const float4*)(feat + (size_t)c * 128 + l * 4);
    float s = a.x * b.x + a.y * b.y + a.z * b.z + a.w * b.w;
    #pragma unroll
    for (int off = 16; off; off >>= 1) s += __shfl_xor(s, off, 32);
    if (l == 0) {
        float sim  = s / (nrm[r] * nrm[c]);
        float kept = (sim >= 0.1f) ? sim : 0.0f;
        simsE[e] = kept;
        if (kept > 0.0f) {
            atomicAdd(&deg1[r], kept);
            atomicAdd(&cnt[c], 1);
        }
    }
}

// vals = exp(dinv1[row]*sim*dinv1[col]) for kept edges; accumulate gcn degree over col
__global__ __launch_bounds__(256) void edge_c_k(float* __restrict__ simsE,
    const int* __restrict__ row, const int* __restrict__ col,
    const float* __restrict__ dinv1, float* __restrict__ deg2, int ecnt) {
    int e = blockIdx.x * 256 + threadIdx.x;
    if (e >= ecnt) return;
    float s = simsE[e];
    if (s > 0.0f) {
        float v = expf(dinv1[row[e]] * s * dinv1[col[e]]);
        simsE[e] = v;                         // buffer now holds vals
        atomicAdd(&deg2[col[e]], v);
    }
}

// bucket kept edges by col: rowC/wC segments per colStart
__global__ __launch_bounds__(256) void edge_fill_k(const float* __restrict__ simsE,
    const int* __restrict__ row, const int* __restrict__ col,
    const float* __restrict__ dinv2, const int* __restrict__ colStart,
    int* __restrict__ cur, int* __restrict__ rowC, float* __restrict__ wC, int ecnt) {
    int e = blockIdx.x * 256 + threadIdx.x;
    if (e >= ecnt) return;
    float v = simsE[e];
    if (v > 0.0f) {
        int r = row[e], c = col[e];
        float w = v * dinv2[r] * dinv2[c];
        int p = colStart[c] + atomicAdd(&cur[c], 1);
        rowC[p] = r; wC[p] = w;
    }
}

// ---------------- exclusive scan of cnt[N] -> colStart[N] ----------------

__global__ __launch_bounds__(256) void scan1_k(const int* __restrict__ cnt,
    int* __restrict__ colStart, int* __restrict__ bsum, int n) {
    __shared__ int tmp[256];
    int i = blockIdx.x * 256 + threadIdx.x;
    int v = (i < n) ? cnt[i] : 0;
    tmp[threadIdx.x] = v; __syncthreads();
    for (int off = 1; off < 256; off <<= 1) {
        int t = (threadIdx.x >= off) ? tmp[threadIdx.x - off] : 0;
        __syncthreads();
        tmp[threadIdx.x] += t;
        __syncthreads();
    }
    if (i < n) colStart[i] = tmp[threadIdx.x] - v;   // exclusive
    if (threadIdx.x == 255) bsum[blockIdx.x] = tmp[255];
}

__global__ __launch_bounds__(512) void scan2_k(int* __restrict__ bsum, int nb) {
    __shared__ int tmp[512];
    int v = (threadIdx.x < nb) ? bsum[threadIdx.x] : 0;
    tmp[threadIdx.x] = v; __syncthreads();
    for (int off = 1; off < 512; off <<= 1) {
        int t = (threadIdx.x >= off) ? tmp[threadIdx.x - off] : 0;
        __syncthreads();
        tmp[threadIdx.x] += t;
        __syncthreads();
    }
    if (threadIdx.x < nb) bsum[threadIdx.x] = tmp[threadIdx.x] - v;  // exclusive
}

__global__ __launch_bounds__(256) void scan3_k(int* __restrict__ colStart,
    const int* __restrict__ bsum, int n) {
    int i = blockIdx.x * 256 + threadIdx.x;
    if (i < n) colStart[i] += bsum[blockIdx.x];
}

// ---------------- GEMM: out[n][:] = A[n][:] @ W (K=128) ----------------

template<int ODIM>
__global__ __launch_bounds__(256) void gemm_k(const float* __restrict__ A,
    const float* __restrict__ W, float* __restrict__ out, int n) {
    constexpr int TPN = ODIM / 4;     // threads per node
    constexpr int NPB = 256 / TPN;    // nodes per block
    __shared__ float Ws[128 * ODIM];
    for (int i = threadIdx.x; i < 128 * ODIM / 4; i += 256)
        ((float4*)Ws)[i] = ((const float4*)W)[i];
    __syncthreads();
    int nid = blockIdx.x * NPB + (int)(threadIdx.x / TPN);
    if (nid >= n) return;
    int dbase = (threadIdx.x % TPN) * 4;
    const float4* a = (const float4*)(A + (size_t)nid * 128);
    float ax = 0.f, ay = 0.f, az = 0.f, aw = 0.f;
    #pragma unroll 4
    for (int k4 = 0; k4 < 32; ++k4) {
        float4 av = a[k4];
        const float* wr = Ws + (k4 * 4) * ODIM + dbase;
        float4 w0 = *(const float4*)(wr);
        float4 w1 = *(const float4*)(wr + ODIM);
        float4 w2 = *(const float4*)(wr + 2 * ODIM);
        float4 w3 = *(const float4*)(wr + 3 * ODIM);
        ax += av.x * w0.x; ay += av.x * w0.y; az += av.x * w0.z; aw += av.x * w0.w;
        ax += av.y * w1.x; ay += av.y * w1.y; az += av.y * w1.z; aw += av.y * w1.w;
        ax += av.z * w2.x; ay += av.z * w2.y; az += av.z * w2.z; aw += av.z * w2.w;
        ax += av.w * w3.x; ay += av.w * w3.y; az += av.w * w3.z; aw += av.w * w3.w;
    }
    float4 r; r.x = ax; r.y = ay; r.z = az; r.w = aw;
    *(float4*)(out + (size_t)nid * ODIM + dbase) = r;
}

// ---------------- fused gather epilogues ----------------

// layer 1: agg = sum_in w*h[row]; x = agg + cself*h[self] + bias; LN; ReLU -> outbuf
// one wave per node, 2 dims per lane. outbuf must NOT alias h.
__global__ __launch_bounds__(256) void gather_ln_k(const float* __restrict__ h,
    const int* __restrict__ rowC, const float* __restrict__ wC,
    const int* __restrict__ colStart, const int* __restrict__ cnt,
    const float* __restrict__ cself, const float* __restrict__ bias,
    const float* __restrict__ g, const float* __restrict__ bln,
    float* __restrict__ outbuf, int n) {
    int wid  = (blockIdx.x * 256 + threadIdx.x) >> 6;
    int lane = threadIdx.x & 63;
    if (wid >= n) return;
    int s0 = colStart[wid], e0 = s0 + cnt[wid];
    float a0 = 0.f, a1 = 0.f;
    for (int j = s0; j < e0; ++j) {
        int r = rowC[j]; float w = wC[j];
        float2 hv = *(const float2*)(h + (size_t)r * 128 + lane * 2);
        a0 += w * hv.x; a1 += w * hv.y;
    }
    float cs = cself[wid];
    float2 hs = *(const float2*)(h + (size_t)wid * 128 + lane * 2);
    float2 vb = *(const float2*)(bias + lane * 2);
    float x0 = a0 + cs * hs.x + vb.x;
    float x1 = a1 + cs * hs.y + vb.y;
    float s = x0 + x1;
    #pragma unroll
    for (int off = 32; off; off >>= 1) s += __shfl_xor(s, off, 64);
    float mu = s * (1.0f / 128.0f);
    float d0 = x0 - mu, d1 = x1 - mu;
    float vv = d0 * d0 + d1 * d1;
    #pragma unroll
    for (int off = 32; off; off >>= 1) vv += __shfl_xor(vv, off, 64);
    float rstd = 1.0f / sqrtf(vv * (1.0f / 128.0f) + LN_EPS);
    float2 vg  = *(const float2*)(g + lane * 2);
    float2 vbl = *(const float2*)(bln + lane * 2);
    float y0 = fmaxf(d0 * rstd * vg.x + vbl.x, 0.0f);
    float y1 = fmaxf(d1 * rstd * vg.y + vbl.y, 0.0f);
    *(float2*)(outbuf + (size_t)wid * 128 + lane * 2) = make_float2(y0, y1);
}

// layer 2: agg = sum_in w*g2[row]; v = agg + cself*g2[self] + b2; log_softmax -> out
// one wave per node, 1 dim per lane (DOUT=64). out must NOT alias g2.
__global__ __launch_bounds__(256) void gather_lsm_k(const float* __restrict__ g2,
    const int* __restrict__ rowC, const float* __restrict__ wC,
    const int* __restrict__ colStart, const int* __restrict__ cnt,
    const float* __restrict__ cself, const float* __restrict__ b2,
    float* __restrict__ out, int n) {
    int wid  = (blockIdx.x * 256 + threadIdx.x) >> 6;
    int lane = threadIdx.x & 63;
    if (wid >= n) return;
    int s0 = colStart[wid], e0 = s0 + cnt[wid];
    float acc = 0.f;
    for (int j = s0; j < e0; ++j) {
        int r = rowC[j]; float w = wC[j];
        acc += w * g2[(size_t)r * 64 + lane];
    }
    float v = acc + cself[wid] * g2[(size_t)wid * 64 + lane] + b2[lane];
    float m = v;
    #pragma unroll
    for (int off = 32; off; off >>= 1) m = fmaxf(m, __shfl_xor(m, off, 64));
    float e = expf(v - m);
    float s = e;
    #pragma unroll
    for (int off = 32; off; off >>= 1) s += __shfl_xor(s, off, 64);
    out[(size_t)wid * 64 + lane] = v - m - logf(s);
}

// ---------------- launch ----------------

extern "C" void kernel_launch(void* const* d_in, const int* in_sizes, int n_in,
                              void* d_out, int out_size, void* d_ws, size_t ws_size,
                              hipStream_t stream) {
    (void)n_in; (void)out_size; (void)ws_size;
    const float* x   = (const float*)d_in[0];
    const int*   row = (const int*)d_in[1];
    const int*   col = (const int*)d_in[2];
    const float* W1  = (const float*)d_in[3];
    const float* b1  = (const float*)d_in[4];
    const float* lng = (const float*)d_in[5];
    const float* lnb = (const float*)d_in[6];
    const float* W2  = (const float*)d_in[7];
    const float* b2  = (const float*)d_in[8];
    float* out = (float*)d_out;

    const int N = in_sizes[0] / 128;
    const int E = in_sizes[1];

    float* ws     = (float*)d_ws;
    float* nrm    = ws;
    float* dinv1  = nrm + N;
    float* wself  = dinv1 + N;
    float* dinv2  = wself + N;
    float* cself  = dinv2 + N;
    float* deg1   = cself + N;        // ---- zero region start
    float* deg2   = deg1 + N;
    int*   cnt    = (int*)(deg2 + N);
    int*   cur    = cnt + N;          // ---- zero region end (4N elems)
    int*   colStart = cur + N;
    int*   bsum   = colStart + N;     // 512 ints
    float* simsE  = (float*)(bsum + 512);
    int*   rowC   = (int*)(simsE + E);
    float* wC     = (float*)(rowC + E);
    float* h1     = wC + E;                  // [N,128]
    float* agg1   = h1 + (size_t)N * 128;    // [N,128] = h2; later g2 lives in h1

    const int nodeBlocks = (N + 255) / 256;
    const int waveBlocks = (N + 3) / 4;            // 1 wave/node, 4 waves/block
    const int edgeBlocks = (E + 255) / 256;
    const int edge32Blk  = (int)(((size_t)E * 32 + 255) / 256);
    const int scanBlocks = nodeBlocks;             // must be <= 512 (N <= 131072)

    // ================= layer 1 =================
    hipMemsetAsync(deg1, 0, 4 * (size_t)N * sizeof(float), stream);

    node_norm_k<<<waveBlocks, 256, 0, stream>>>(x, nrm, N);
    edge_dot_k<<<edge32Blk, 256, 0, stream>>>(x, row, col, nrm, simsE, deg1, cnt, E);
    node_b_k<<<nodeBlocks, 256, 0, stream>>>(deg1, cnt, dinv1, wself, N);
    edge_c_k<<<edgeBlocks, 256, 0, stream>>>(simsE, row, col, dinv1, deg2, E);
    node_d_k<<<nodeBlocks, 256, 0, stream>>>(deg2, wself, dinv2, cself, N);
    scan1_k<<<scanBlocks, 256, 0, stream>>>(cnt, colStart, bsum, N);
    scan2_k<<<1, 512, 0, stream>>>(bsum, scanBlocks);
    scan3_k<<<scanBlocks, 256, 0, stream>>>(colStart, bsum, N);
    edge_fill_k<<<edgeBlocks, 256, 0, stream>>>(simsE, row, col, dinv2, colStart, cur, rowC, wC, E);

    gemm_k<128><<<(N + 7) / 8, 256, 0, stream>>>(x, W1, h1, N);
    gather_ln_k<<<waveBlocks, 256, 0, stream>>>(h1, rowC, wC, colStart, cnt, cself,
                                                b1, lng, lnb, agg1, N);   // agg1 := h2

    // ================= layer 2 =================
    hipMemsetAsync(deg1, 0, 4 * (size_t)N * sizeof(float), stream);

    node_norm_k<<<waveBlocks, 256, 0, stream>>>(agg1, nrm, N);
    edge_dot_k<<<edge32Blk, 256, 0, stream>>>(agg1, row, col, nrm, simsE, deg1, cnt, E);
    node_b_k<<<nodeBlocks, 256, 0, stream>>>(deg1, cnt, dinv1, wself, N);
    edge_c_k<<<edgeBlocks, 256, 0, stream>>>(simsE, row, col, dinv1, deg2, E);
    node_d_k<<<nodeBlocks, 256, 0, stream>>>(deg2, wself, dinv2, cself, N);
    scan1_k<<<scanBlocks, 256, 0, stream>>>(cnt, colStart, bsum, N);
    scan2_k<<<1, 512, 0, stream>>>(bsum, scanBlocks);
    scan3_k<<<scanBlocks, 256, 0, stream>>>(colStart, bsum, N);
    edge_fill_k<<<edgeBlocks, 256, 0, stream>>>(simsE, row, col, dinv2, colStart, cur, rowC, wC, E);

    gemm_k<64><<<(N + 15) / 16, 256, 0, stream>>>(agg1, W2, h1, N);       // h1 := g2
    gather_lsm_k<<<waveBlocks, 256, 0, stream>>>(h1, rowC, wC, colStart, cnt, cself,
                                                 b2, out, N);
}

// Round 3
// 974.298 us; speedup vs baseline: 2.0135x; 1.2513x over previous
//
#include <hip/hip_runtime.h>
#include <math.h>

#define EPSF 1e-8f
#define LN_EPS 1e-5f

// ---------------- node kernels ----------------

// one wave (64 lanes) per node, 2 floats per lane
__global__ __launch_bounds__(256) void node_norm_k(const float* __restrict__ feat,
                                                   float* __restrict__ nrm, int n) {
    int wid  = (blockIdx.x * 256 + threadIdx.x) >> 6;
    int lane = threadIdx.x & 63;
    if (wid >= n) return;
    float2 v = *(const float2*)(feat + (size_t)wid * 128 + lane * 2);
    float s = v.x * v.x + v.y * v.y;
    #pragma unroll
    for (int off = 32; off; off >>= 1) s += __shfl_xor(s, off, 64);
    if (lane == 0) nrm[wid] = fmaxf(sqrtf(s), EPSF);
}

__global__ __launch_bounds__(256) void node_b_k(const float* __restrict__ deg1,
                                                float* __restrict__ dinv1, int n) {
    int i = blockIdx.x * 256 + threadIdx.x;
    if (i >= n) return;
    float d = deg1[i];
    dinv1[i] = (d > 0.0f) ? 1.0f / sqrtf(d) : 0.0f;
}

// ---------------- one-time CSR build (edge list identical for both layers) ----------------

__global__ __launch_bounds__(256) void count_k(const int* __restrict__ col,
                                               int* __restrict__ cntAll, int ecnt) {
    int e = blockIdx.x * 256 + threadIdx.x;
    if (e < ecnt) atomicAdd(&cntAll[col[e]], 1);
}

__global__ __launch_bounds__(256) void scan1_k(const int* __restrict__ cnt,
    int* __restrict__ colStart, int* __restrict__ bsum, int n) {
    __shared__ int tmp[256];
    int i = blockIdx.x * 256 + threadIdx.x;
    int v = (i < n) ? cnt[i] : 0;
    tmp[threadIdx.x] = v; __syncthreads();
    for (int off = 1; off < 256; off <<= 1) {
        int t = (threadIdx.x >= off) ? tmp[threadIdx.x - off] : 0;
        __syncthreads();
        tmp[threadIdx.x] += t;
        __syncthreads();
    }
    if (i < n) colStart[i] = tmp[threadIdx.x] - v;   // exclusive
    if (threadIdx.x == 255) bsum[blockIdx.x] = tmp[255];
}

__global__ __launch_bounds__(512) void scan2_k(int* __restrict__ bsum, int nb) {
    __shared__ int tmp[512];
    int v = (threadIdx.x < nb) ? bsum[threadIdx.x] : 0;
    tmp[threadIdx.x] = v; __syncthreads();
    for (int off = 1; off < 512; off <<= 1) {
        int t = (threadIdx.x >= off) ? tmp[threadIdx.x - off] : 0;
        __syncthreads();
        tmp[threadIdx.x] += t;
        __syncthreads();
    }
    if (threadIdx.x < nb) bsum[threadIdx.x] = tmp[threadIdx.x] - v;  // exclusive
}

__global__ __launch_bounds__(256) void scan3_k(int* __restrict__ colStart,
    const int* __restrict__ bsum, int n) {
    int i = blockIdx.x * 256 + threadIdx.x;
    if (i < n) colStart[i] += bsum[blockIdx.x];
}

__global__ __launch_bounds__(256) void fill_k(const int* __restrict__ row,
    const int* __restrict__ col, const int* __restrict__ startAll,
    int* __restrict__ cur, int* __restrict__ rowAll, int ecnt) {
    int e = blockIdx.x * 256 + threadIdx.x;
    if (e >= ecnt) return;
    int c = col[e];
    int p = startAll[c] + atomicAdd(&cur[c], 1);
    rowAll[p] = row[e];
}

// ---------------- edge phase A: cosine sims in CSR order ----------------
// one wave per col node; col feature in registers (float4/lane over 32 lanes),
// two edges in flight (half-wave each). Writes sims (CSR order), deg1[row] atomics,
// wself[col] directly (kept-count known in-wave).
__global__ __launch_bounds__(256) void edge_dot_csr_k(const float* __restrict__ feat,
    const int* __restrict__ rowAll, const int* __restrict__ startAll,
    const int* __restrict__ cntAll, const float* __restrict__ nrm,
    float* __restrict__ sims, float* __restrict__ deg1,
    float* __restrict__ wself, int n) {
    int wid  = (blockIdx.x * 256 + threadIdx.x) >> 6;
    int lane = threadIdx.x & 63;
    if (wid >= n) return;
    int s0 = startAll[wid], cnt = cntAll[wid];
    int half = lane >> 5, l = lane & 31;
    float4 fc = *(const float4*)(feat + (size_t)wid * 128 + l * 4);
    float nc = nrm[wid];
    int kept = 0;
    for (int jj = 0; jj < cnt; jj += 2) {
        int j = jj + half;
        if (j < cnt) {
            int r = rowAll[s0 + j];
            float4 fr = *(const float4*)(feat + (size_t)r * 128 + l * 4);
            float p = fr.x * fc.x + fr.y * fc.y + fr.z * fc.z + fr.w * fc.w;
            #pragma unroll
            for (int off = 16; off; off >>= 1) p += __shfl_xor(p, off, 64);
            float sim = p / (nrm[r] * nc);
            float kv_ = (sim >= 0.1f) ? sim : 0.0f;
            if (l == 0) {
                sims[s0 + j] = kv_;
                if (kv_ > 0.0f) atomicAdd(&deg1[r], kv_);
            }
            if (kv_ > 0.0f) kept++;
        }
    }
    kept += __shfl_xor(kept, 32, 64);
    if (lane == 0) wself[wid] = expf(1.0f / ((float)kept + 1.0f));
}

// ---------------- edge phase B: vals + in-wave deg2 + compaction ----------------
// one wave per col node, lane per edge. No atomics. Produces packed (row,val)
// records for kept edges, kept count, and dinv2/cself (deg2 complete in-wave).
__global__ __launch_bounds__(256) void edge_c_csr_k(const float* __restrict__ sims,
    const int* __restrict__ rowAll, const int* __restrict__ startAll,
    const int* __restrict__ cntAll, const float* __restrict__ dinv1,
    const float* __restrict__ wself, int2* __restrict__ kv,
    int* __restrict__ cntK, float* __restrict__ dinv2,
    float* __restrict__ cself, int n) {
    int wid  = (blockIdx.x * 256 + threadIdx.x) >> 6;
    int lane = threadIdx.x & 63;
    if (wid >= n) return;
    int s0 = startAll[wid], cnt = cntAll[wid];
    float d1c = dinv1[wid];
    float vsum = 0.0f; int kc = 0;
    for (int jj = 0; jj < cnt; jj += 64) {
        int j = jj + lane;
        bool keep = false; int r = 0; float v = 0.0f;
        if (j < cnt) {
            float s = sims[s0 + j];
            if (s > 0.0f) { r = rowAll[s0 + j]; v = expf(dinv1[r] * s * d1c); keep = true; }
        }
        unsigned long long m = __ballot(keep ? 1 : 0);
        if (keep) {
            int pre = __popcll(m & ((1ull << lane) - 1ull));
            int2 pk; pk.x = r; pk.y = __float_as_int(v);
            kv[s0 + kc + pre] = pk;
            vsum += v;
        }
        kc += __popcll(m);
    }
    #pragma unroll
    for (int off = 32; off; off >>= 1) vsum += __shfl_xor(vsum, off, 64);
    if (lane == 0) {
        float dg = vsum + wself[wid];          // always > 0
        float di = 1.0f / sqrtf(dg);
        dinv2[wid] = di;
        cself[wid] = di * wself[wid];          // self term uses scaled-h, so one di here
        cntK[wid]  = kc;
    }
}

// ---------------- GEMM: out[n][:] = (A[n][:] @ W) * scale[n]  (K=128) ----------------

template<int ODIM>
__global__ __launch_bounds__(256) void gemm_k(const float* __restrict__ A,
    const float* __restrict__ W, const float* __restrict__ scale,
    float* __restrict__ out, int n) {
    constexpr int TPN = ODIM / 4;
    constexpr int NPB = 256 / TPN;
    __shared__ float Ws[128 * ODIM];
    for (int i = threadIdx.x; i < 128 * ODIM / 4; i += 256)
        ((float4*)Ws)[i] = ((const float4*)W)[i];
    __syncthreads();
    int nid = blockIdx.x * NPB + (int)(threadIdx.x / TPN);
    if (nid >= n) return;
    int dbase = (threadIdx.x % TPN) * 4;
    const float4* a = (const float4*)(A + (size_t)nid * 128);
    float ax = 0.f, ay = 0.f, az = 0.f, aw = 0.f;
    #pragma unroll 4
    for (int k4 = 0; k4 < 32; ++k4) {
        float4 av = a[k4];
        const float* wr = Ws + (k4 * 4) * ODIM + dbase;
        float4 w0 = *(const float4*)(wr);
        float4 w1 = *(const float4*)(wr + ODIM);
        float4 w2 = *(const float4*)(wr + 2 * ODIM);
        float4 w3 = *(const float4*)(wr + 3 * ODIM);
        ax += av.x * w0.x; ay += av.x * w0.y; az += av.x * w0.z; aw += av.x * w0.w;
        ax += av.y * w1.x; ay += av.y * w1.y; az += av.y * w1.z; aw += av.y * w1.w;
        ax += av.z * w2.x; ay += av.z * w2.y; az += av.z * w2.z; aw += av.z * w2.w;
        ax += av.w * w3.x; ay += av.w * w3.y; az += av.w * w3.z; aw += av.w * w3.w;
    }
    float sc = scale[nid];
    float4 r; r.x = ax * sc; r.y = ay * sc; r.z = az * sc; r.w = aw * sc;
    *(float4*)(out + (size_t)nid * ODIM + dbase) = r;
}

// ---------------- fused gather epilogues (inputs pre-scaled by dinv2[row]) ----------------

// layer 1: x = dinv2[c]*sum(val*hs[row]) + cself*hs[c] + bias; LN; ReLU -> outbuf
__global__ __launch_bounds__(256) void gather_ln_k(const float* __restrict__ hs,
    const int2* __restrict__ kv, const int* __restrict__ startAll,
    const int* __restrict__ cntK, const float* __restrict__ dinv2,
    const float* __restrict__ cself, const float* __restrict__ bias,
    const float* __restrict__ g, const float* __restrict__ bln,
    float* __restrict__ outbuf, int n) {
    int wid  = (blockIdx.x * 256 + threadIdx.x) >> 6;
    int lane = threadIdx.x & 63;
    if (wid >= n) return;
    int s0 = startAll[wid], k = cntK[wid];
    float a0 = 0.f, a1 = 0.f;
    int j = 0;
    for (; j + 1 < k; j += 2) {
        int2 p0 = kv[s0 + j], p1 = kv[s0 + j + 1];
        float2 h0 = *(const float2*)(hs + (size_t)p0.x * 128 + lane * 2);
        float2 h1 = *(const float2*)(hs + (size_t)p1.x * 128 + lane * 2);
        float v0 = __int_as_float(p0.y), v1 = __int_as_float(p1.y);
        a0 += v0 * h0.x + v1 * h1.x;
        a1 += v0 * h0.y + v1 * h1.y;
    }
    if (j < k) {
        int2 p0 = kv[s0 + j];
        float2 h0 = *(const float2*)(hs + (size_t)p0.x * 128 + lane * 2);
        float v0 = __int_as_float(p0.y);
        a0 += v0 * h0.x; a1 += v0 * h0.y;
    }
    float di = dinv2[wid], cs = cself[wid];
    float2 hsv = *(const float2*)(hs + (size_t)wid * 128 + lane * 2);
    float2 vb  = *(const float2*)(bias + lane * 2);
    float x0 = di * a0 + cs * hsv.x + vb.x;
    float x1 = di * a1 + cs * hsv.y + vb.y;
    float s = x0 + x1;
    #pragma unroll
    for (int off = 32; off; off >>= 1) s += __shfl_xor(s, off, 64);
    float mu = s * (1.0f / 128.0f);
    float d0 = x0 - mu, d1 = x1 - mu;
    float vv = d0 * d0 + d1 * d1;
    #pragma unroll
    for (int off = 32; off; off >>= 1) vv += __shfl_xor(vv, off, 64);
    float rstd = 1.0f / sqrtf(vv * (1.0f / 128.0f) + LN_EPS);
    float2 vg  = *(const float2*)(g + lane * 2);
    float2 vbl = *(const float2*)(bln + lane * 2);
    float y0 = fmaxf(d0 * rstd * vg.x + vbl.x, 0.0f);
    float y1 = fmaxf(d1 * rstd * vg.y + vbl.y, 0.0f);
    *(float2*)(outbuf + (size_t)wid * 128 + lane * 2) = make_float2(y0, y1);
}

// layer 2: v = dinv2[c]*sum(val*g2s[row]) + cself*g2s[c] + b2; log_softmax -> out
__global__ __launch_bounds__(256) void gather_lsm_k(const float* __restrict__ g2s,
    const int2* __restrict__ kv, const int* __restrict__ startAll,
    const int* __restrict__ cntK, const float* __restrict__ dinv2,
    const float* __restrict__ cself, const float* __restrict__ b2,
    float* __restrict__ out, int n) {
    int wid  = (blockIdx.x * 256 + threadIdx.x) >> 6;
    int lane = threadIdx.x & 63;
    if (wid >= n) return;
    int s0 = startAll[wid], k = cntK[wid];
    float acc = 0.f;
    int j = 0;
    for (; j + 1 < k; j += 2) {
        int2 p0 = kv[s0 + j], p1 = kv[s0 + j + 1];
        float v0 = __int_as_float(p0.y), v1 = __int_as_float(p1.y);
        acc += v0 * g2s[(size_t)p0.x * 64 + lane] + v1 * g2s[(size_t)p1.x * 64 + lane];
    }
    if (j < k) {
        int2 p0 = kv[s0 + j];
        acc += __int_as_float(p0.y) * g2s[(size_t)p0.x * 64 + lane];
    }
    float v = dinv2[wid] * acc + cself[wid] * g2s[(size_t)wid * 64 + lane] + b2[lane];
    float m = v;
    #pragma unroll
    for (int off = 32; off; off >>= 1) m = fmaxf(m, __shfl_xor(m, off, 64));
    float e = expf(v - m);
    float s = e;
    #pragma unroll
    for (int off = 32; off; off >>= 1) s += __shfl_xor(s, off, 64);
    out[(size_t)wid * 64 + lane] = v - m - logf(s);
}

// ---------------- launch ----------------

extern "C" void kernel_launch(void* const* d_in, const int* in_sizes, int n_in,
                              void* d_out, int out_size, void* d_ws, size_t ws_size,
                              hipStream_t stream) {
    (void)n_in; (void)out_size; (void)ws_size;
    const float* x   = (const float*)d_in[0];
    const int*   row = (const int*)d_in[1];
    const int*   col = (const int*)d_in[2];
    const float* W1  = (const float*)d_in[3];
    const float* b1  = (const float*)d_in[4];
    const float* lng = (const float*)d_in[5];
    const float* lnb = (const float*)d_in[6];
    const float* W2  = (const float*)d_in[7];
    const float* b2  = (const float*)d_in[8];
    float* out = (float*)d_out;

    const int N = in_sizes[0] / 128;
    const int E = in_sizes[1];

    int*   cntAll   = (int*)d_ws;
    int*   startAll = cntAll + N;
    int*   bsum     = startAll + N;            // 512 ints
    float* nrm      = (float*)(bsum + 512);
    float* deg1     = nrm + N;
    float* dinv1    = deg1 + N;
    float* wself    = dinv1 + N;
    float* dinv2    = wself + N;
    float* cself    = dinv2 + N;
    int*   cntK     = (int*)(cself + N);       // CSR-build cursor, then kept counts
    int*   rowAll   = cntK + N;                // [E]
    int2*  kvp      = (int2*)(rowAll + E);     // [E] packed (row, val)
    float* big      = (float*)(kvp + E);       // [128N] region, multi-use:
    float* sims     = big;                     //   [E]   (dead before hs written)
    float* hs       = big;                     //   [128N] layer-1 scaled h
    float* g2s      = big + (size_t)64 * N;    //   [64N] layer-2 scaled g (disjoint from sims)
    float* h2       = big + (size_t)128 * N;   // [128N] layer-1 output

    const int nodeBlocks = (N + 255) / 256;
    const int waveBlocks = (N + 3) / 4;
    const int edgeBlocks = (E + 255) / 256;
    const int scanBlocks = nodeBlocks;         // <= 512 for N <= 131072

    // ---- one-time CSR build (shared by both layers) ----
    hipMemsetAsync(cntAll, 0, (size_t)N * sizeof(int), stream);
    count_k<<<edgeBlocks, 256, 0, stream>>>(col, cntAll, E);
    scan1_k<<<scanBlocks, 256, 0, stream>>>(cntAll, startAll, bsum, N);
    scan2_k<<<1, 512, 0, stream>>>(bsum, scanBlocks);
    scan3_k<<<scanBlocks, 256, 0, stream>>>(startAll, bsum, N);
    hipMemsetAsync(cntK, 0, (size_t)N * sizeof(int), stream);
    fill_k<<<edgeBlocks, 256, 0, stream>>>(row, col, startAll, cntK, rowAll, E);

    // ================= layer 1 =================
    hipMemsetAsync(deg1, 0, (size_t)N * sizeof(float), stream);
    node_norm_k<<<waveBlocks, 256, 0, stream>>>(x, nrm, N);
    edge_dot_csr_k<<<waveBlocks, 256, 0, stream>>>(x, rowAll, startAll, cntAll, nrm,
                                                   sims, deg1, wself, N);
    node_b_k<<<nodeBlocks, 256, 0, stream>>>(deg1, dinv1, N);
    edge_c_csr_k<<<waveBlocks, 256, 0, stream>>>(sims, rowAll, startAll, cntAll, dinv1,
                                                 wself, kvp, cntK, dinv2, cself, N);
    gemm_k<128><<<(N + 7) / 8, 256, 0, stream>>>(x, W1, dinv2, hs, N);
    gather_ln_k<<<waveBlocks, 256, 0, stream>>>(hs, kvp, startAll, cntK, dinv2, cself,
                                                b1, lng, lnb, h2, N);

    // ================= layer 2 =================
    hipMemsetAsync(deg1, 0, (size_t)N * sizeof(float), stream);
    node_norm_k<<<waveBlocks, 256, 0, stream>>>(h2, nrm, N);
    edge_dot_csr_k<<<waveBlocks, 256, 0, stream>>>(h2, rowAll, startAll, cntAll, nrm,
                                                   sims, deg1, wself, N);
    node_b_k<<<nodeBlocks, 256, 0, stream>>>(deg1, dinv1, N);
    edge_c_csr_k<<<waveBlocks, 256, 0, stream>>>(sims, rowAll, startAll, cntAll, dinv1,
                                                 wself, kvp, cntK, dinv2, cself, N);
    gemm_k<64><<<(N + 15) / 16, 256, 0, stream>>>(h2, W2, dinv2, g2s, N);
    gather_lsm_k<<<waveBlocks, 256, 0, stream>>>(g2s, kvp, startAll, cntK, dinv2, cself,
                                                 b2, out, N);
}